// Round 2
// baseline (136.629 us; speedup 1.0000x reference)
//
#include <hip/hip_runtime.h>
#include <hip/hip_bf16.h>
#include <stdint.h>

// B=8, C=256, H=W=64 (N=4096), T=512
// out0 = F_s + (softmax(Fs_t @ Ft^T / sqrt(T)) @ Ft)^T_layout   [B][C][N] fp32
// out1 = P^T @ Fs_t                                             [B][T][C] fp32

typedef __attribute__((ext_vector_type(8))) short short8v;   // 8 bf16
typedef __attribute__((ext_vector_type(4))) float float4v;

#define MFMA16(a, b, c) __builtin_amdgcn_mfma_f32_16x16x32_bf16(a, b, c, 0, 0, 0)
#define SCALE 0.04419417382415922f  // 1/sqrt(512)

static __device__ __forceinline__ unsigned short f2bf(float f) {
  union { float f; uint32_t u; } v; v.f = f;
  uint32_t r = v.u + 0x7fffu + ((v.u >> 16) & 1u);   // RNE
  return (unsigned short)(r >> 16);
}

// ---------- cast + transpose: src [Z][R][Cd] f32 -> dstC [Z][R][Cd] bf16, dstT [Z][Cd][R] bf16
__global__ __launch_bounds__(256) void k_cast_transpose(
    const float* __restrict__ src, unsigned short* __restrict__ dstC,
    unsigned short* __restrict__ dstT, int R, int Cd) {
  __shared__ unsigned short tile[32][33];
  const size_t zoff = (size_t)blockIdx.z * R * Cd;
  const float* s = src + zoff;
  unsigned short* dc = dstC + zoff;
  unsigned short* dt = dstT + zoff;
  const int c0 = blockIdx.x * 32, r0 = blockIdx.y * 32;
  const int tid = threadIdx.x;
  const int r = tid >> 3, c4 = (tid & 7) * 4;

  float4 v = *(const float4*)&s[(size_t)(r0 + r) * Cd + c0 + c4];
  ushort4 bq;
  bq.x = f2bf(v.x); bq.y = f2bf(v.y); bq.z = f2bf(v.z); bq.w = f2bf(v.w);
  *(ushort4*)&dc[(size_t)(r0 + r) * Cd + c0 + c4] = bq;
  tile[r][c4 + 0] = bq.x; tile[r][c4 + 1] = bq.y;
  tile[r][c4 + 2] = bq.z; tile[r][c4 + 3] = bq.w;
  __syncthreads();
  ushort4 o;
  o.x = tile[c4 + 0][r]; o.y = tile[c4 + 1][r];
  o.z = tile[c4 + 2][r]; o.w = tile[c4 + 3][r];
  *(ushort4*)&dt[(size_t)(c0 + r) * R + r0 + c4] = o;
}

// ---------- fused S + softmax + PT write + O_s  ----------
// grid: (128 n-blocks, 8 batches), 256 threads (4 waves)
// LDS layout (bytes):
//   [0,20480)      Ks [256][40]        (phase 1)      } overlaid later by
//   [20480,37376)  Qs [32][264]        (phase 1)      } Plds [32][520] (33280 B)
//   [37376,38400)  red float[8][32]    (softmax)
//   [33280,53760)  VTs [256][40]       (phase 3; red dead by then)
//   [0,33280)      Olds f32 [32][260]  (epilogue; Plds dead)
__global__ __launch_bounds__(256) void k_attn(
    const unsigned short* __restrict__ Qg, const unsigned short* __restrict__ Kg,
    const unsigned short* __restrict__ VTg, const float* __restrict__ Fs,
    float* __restrict__ out0, unsigned short* __restrict__ PTg) {
  __shared__ char smem[53760];
  unsigned short* sU = (unsigned short*)smem;
  unsigned short* Ks = sU;                  // [256][40]
  unsigned short* Qs = sU + 10240;          // [32][264]
  float* red = (float*)(smem + 37376);      // [8][32]
  unsigned short* Plds = sU;                // [32][520]
  unsigned short* VTs = sU + 16640;         // [256][40] @ byte 33280
  float* Olds = (float*)smem;               // [32][260]

  const int tid = threadIdx.x;
  const int wave = tid >> 6, lane = tid & 63;
  const int l16 = lane & 15, lhi = lane >> 4;
  const int b = blockIdx.y, n0 = blockIdx.x * 32;

  const unsigned short* Qb = Qg + (size_t)b * 4096 * 256;
  const unsigned short* Kb = Kg + (size_t)b * 512 * 256;
  const unsigned short* VTb = VTg + (size_t)b * 256 * 512;

  // stage Q fully: [32][256] -> Qs [32][264]
#pragma unroll
  for (int i = 0; i < 4; i++) {
    int chunk = tid + i * 256;
    int row = chunk >> 5, col = (chunk & 31) * 8;
    *(int4*)(Qs + row * 264 + col) = *(const int4*)(Qb + (size_t)(n0 + row) * 256 + col);
  }

  float4v acc[2][8];
#pragma unroll
  for (int mi = 0; mi < 2; mi++)
#pragma unroll
    for (int tj = 0; tj < 8; tj++) acc[mi][tj] = (float4v)0.f;

  // ---- phase 1: S = Q @ K^T ----
#pragma unroll
  for (int th = 0; th < 2; th++) {
#pragma unroll 1
    for (int kk = 0; kk < 8; kk++) {
      __syncthreads();
#pragma unroll
      for (int i = 0; i < 4; i++) {
        int chunk = tid + i * 256;
        int row = chunk >> 2, col = (chunk & 3) * 8;
        *(int4*)(Ks + row * 40 + col) =
            *(const int4*)(Kb + (size_t)(th * 256 + row) * 256 + kk * 32 + col);
      }
      __syncthreads();
      short8v a0 = *(const short8v*)(Qs + l16 * 264 + kk * 32 + lhi * 8);
      short8v a1 = *(const short8v*)(Qs + (l16 + 16) * 264 + kk * 32 + lhi * 8);
#pragma unroll
      for (int ti = 0; ti < 4; ti++) {
        short8v bf = *(const short8v*)(Ks + (wave * 64 + ti * 16 + l16) * 40 + lhi * 8);
        acc[0][th * 4 + ti] = MFMA16(a0, bf, acc[0][th * 4 + ti]);
        acc[1][th * 4 + ti] = MFMA16(a1, bf, acc[1][th * 4 + ti]);
      }
    }
  }
  __syncthreads();

  // ---- softmax (exact, full T=512 per row) ----
#pragma unroll
  for (int mi = 0; mi < 2; mi++)
#pragma unroll
    for (int tj = 0; tj < 8; tj++)
#pragma unroll
      for (int i = 0; i < 4; i++) acc[mi][tj][i] *= SCALE;

  float mrow[2][4];
#pragma unroll
  for (int mi = 0; mi < 2; mi++)
#pragma unroll
    for (int i = 0; i < 4; i++) {
      float m = acc[mi][0][i];
#pragma unroll
      for (int tj = 1; tj < 8; tj++) m = fmaxf(m, acc[mi][tj][i]);
      m = fmaxf(m, __shfl_xor(m, 1));
      m = fmaxf(m, __shfl_xor(m, 2));
      m = fmaxf(m, __shfl_xor(m, 4));
      m = fmaxf(m, __shfl_xor(m, 8));
      mrow[mi][i] = m;
    }
  if (l16 == 0) {
#pragma unroll
    for (int mi = 0; mi < 2; mi++)
#pragma unroll
      for (int i = 0; i < 4; i++)
        red[wave * 32 + mi * 16 + lhi * 4 + i] = mrow[mi][i];
  }
  __syncthreads();
#pragma unroll
  for (int mi = 0; mi < 2; mi++)
#pragma unroll
    for (int i = 0; i < 4; i++) {
      int r = mi * 16 + lhi * 4 + i;
      mrow[mi][i] = fmaxf(fmaxf(red[r], red[32 + r]), fmaxf(red[64 + r], red[96 + r]));
    }
  float srow[2][4];
#pragma unroll
  for (int mi = 0; mi < 2; mi++)
#pragma unroll
    for (int i = 0; i < 4; i++) {
      float s = 0.f;
#pragma unroll
      for (int tj = 0; tj < 8; tj++) {
        float p = __expf(acc[mi][tj][i] - mrow[mi][i]);
        acc[mi][tj][i] = p;
        s += p;
      }
      s += __shfl_xor(s, 1); s += __shfl_xor(s, 2);
      s += __shfl_xor(s, 4); s += __shfl_xor(s, 8);
      srow[mi][i] = s;
    }
  if (l16 == 0) {
#pragma unroll
    for (int mi = 0; mi < 2; mi++)
#pragma unroll
      for (int i = 0; i < 4; i++)
        red[128 + wave * 32 + mi * 16 + lhi * 4 + i] = srow[mi][i];
  }
  __syncthreads();
  float inv[2][4];
#pragma unroll
  for (int mi = 0; mi < 2; mi++)
#pragma unroll
    for (int i = 0; i < 4; i++) {
      int r = mi * 16 + lhi * 4 + i;
      float l = red[128 + r] + red[160 + r] + red[192 + r] + red[224 + r];
      inv[mi][i] = 1.0f / l;
    }
  __syncthreads();  // all waves done with red/Ks/Qs before Plds overlay

  // ---- write P to LDS (bf16, padded) ----
#pragma unroll
  for (int mi = 0; mi < 2; mi++)
#pragma unroll
    for (int th = 0; th < 2; th++)
#pragma unroll
      for (int ti = 0; ti < 4; ti++)
#pragma unroll
        for (int i = 0; i < 4; i++) {
          int r = mi * 16 + lhi * 4 + i;
          int t = th * 256 + wave * 64 + ti * 16 + l16;
          Plds[r * 520 + t] = f2bf(acc[mi][th * 4 + ti][i] * inv[mi][i]);
        }
  __syncthreads();

  // ---- write PT to global: PT[b][t][n0..n0+31] ----
  unsigned short* PTb = PTg + (size_t)b * 512 * 4096;
#pragma unroll 1
  for (int rep = 0; rep < 2; rep++) {
    int t = rep * 256 + tid;
    unsigned short tmp[32];
#pragma unroll
    for (int n = 0; n < 32; n++) tmp[n] = Plds[n * 520 + t];
#pragma unroll
    for (int j = 0; j < 4; j++)
      *(int4*)(PTb + (size_t)t * 4096 + n0 + j * 8) = *(int4*)&tmp[j * 8];
  }

  // ---- phase 3: O_s = P @ V (V = F_t, via VT [c][t]) ----
  float4v oacc[2][4];
#pragma unroll
  for (int mi = 0; mi < 2; mi++)
#pragma unroll
    for (int ci = 0; ci < 4; ci++) oacc[mi][ci] = (float4v)0.f;

#pragma unroll 1
  for (int tc = 0; tc < 16; tc++) {
    __syncthreads();
#pragma unroll
    for (int i = 0; i < 4; i++) {
      int chunk = tid + i * 256;
      int row = chunk >> 2, col = (chunk & 3) * 8;
      *(int4*)(VTs + row * 40 + col) =
          *(const int4*)(VTb + (size_t)row * 512 + tc * 32 + col);
    }
    __syncthreads();
    short8v pa0 = *(const short8v*)(Plds + l16 * 520 + tc * 32 + lhi * 8);
    short8v pa1 = *(const short8v*)(Plds + (l16 + 16) * 520 + tc * 32 + lhi * 8);
#pragma unroll
    for (int ci = 0; ci < 4; ci++) {
      short8v bf = *(const short8v*)(VTs + (wave * 64 + ci * 16 + l16) * 40 + lhi * 8);
      oacc[0][ci] = MFMA16(pa0, bf, oacc[0][ci]);
      oacc[1][ci] = MFMA16(pa1, bf, oacc[1][ci]);
    }
  }
  __syncthreads();

  // ---- epilogue: transpose via LDS, add F_s, write out0 [b][c][n] ----
#pragma unroll
  for (int mi = 0; mi < 2; mi++)
#pragma unroll
    for (int ci = 0; ci < 4; ci++)
#pragma unroll
      for (int i = 0; i < 4; i++)
        Olds[(mi * 16 + lhi * 4 + i) * 260 + wave * 64 + ci * 16 + l16] = oacc[mi][ci][i];
  __syncthreads();
  const float* Fsb = Fs + (size_t)b * 256 * 4096;
  float* o0 = out0 + (size_t)b * 256 * 4096;
#pragma unroll
  for (int i8 = 0; i8 < 8; i8++) {
    float4 f = *(const float4*)&Fsb[(size_t)tid * 4096 + n0 + i8 * 4];
    float4 o;
    o.x = Olds[(i8 * 4 + 0) * 260 + tid] + f.x;
    o.y = Olds[(i8 * 4 + 1) * 260 + tid] + f.y;
    o.z = Olds[(i8 * 4 + 2) * 260 + tid] + f.z;
    o.w = Olds[(i8 * 4 + 3) * 260 + tid] + f.w;
    *(float4*)&o0[(size_t)tid * 4096 + n0 + i8 * 4] = o;
  }
}

// ---------- F_t_updated = PT @ Q  (B-operand from QT), split-K=4, atomic ----------
// grid: (8 t-blocks, 4 c-blocks, 8 batches * 4 k-slices), 256 threads
__global__ __launch_bounds__(256) void k_ptq(
    const unsigned short* __restrict__ PTg, const unsigned short* __restrict__ QTg,
    float* __restrict__ out1) {
  __shared__ unsigned short As[64 * 72];
  __shared__ unsigned short Bs[64 * 72];
  const int tid = threadIdx.x;
  const int wave = tid >> 6, lane = tid & 63;
  const int l16 = lane & 15, lhi = lane >> 4;
  const int t0 = blockIdx.x * 64, c0 = blockIdx.y * 64;
  const int b = blockIdx.z >> 2, ksl = blockIdx.z & 3;
  const unsigned short* PTb = PTg + (size_t)b * 512 * 4096 + ksl * 1024;
  const unsigned short* QTb = QTg + (size_t)b * 256 * 4096 + ksl * 1024;
  const int wr = wave >> 1, wc = wave & 1;

  float4v acc[2][2];
#pragma unroll
  for (int mi = 0; mi < 2; mi++)
#pragma unroll
    for (int ni = 0; ni < 2; ni++) acc[mi][ni] = (float4v)0.f;

#pragma unroll 1
  for (int kk = 0; kk < 16; kk++) {
    __syncthreads();
#pragma unroll
    for (int i = 0; i < 2; i++) {
      int chunk = tid + i * 256;
      int row = chunk >> 3, col = (chunk & 7) * 8;
      *(int4*)(As + row * 72 + col) =
          *(const int4*)(PTb + (size_t)(t0 + row) * 4096 + kk * 64 + col);
      *(int4*)(Bs + row * 72 + col) =
          *(const int4*)(QTb + (size_t)(c0 + row) * 4096 + kk * 64 + col);
    }
    __syncthreads();
#pragma unroll
    for (int ks = 0; ks < 2; ks++) {
      short8v a0 = *(const short8v*)(As + (wr * 32 + l16) * 72 + ks * 32 + lhi * 8);
      short8v a1 = *(const short8v*)(As + (wr * 32 + 16 + l16) * 72 + ks * 32 + lhi * 8);
      short8v b0 = *(const short8v*)(Bs + (wc * 32 + l16) * 72 + ks * 32 + lhi * 8);
      short8v b1 = *(const short8v*)(Bs + (wc * 32 + 16 + l16) * 72 + ks * 32 + lhi * 8);
      acc[0][0] = MFMA16(a0, b0, acc[0][0]);
      acc[0][1] = MFMA16(a0, b1, acc[0][1]);
      acc[1][0] = MFMA16(a1, b0, acc[1][0]);
      acc[1][1] = MFMA16(a1, b1, acc[1][1]);
    }
  }
#pragma unroll
  for (int mi = 0; mi < 2; mi++)
#pragma unroll
    for (int ni = 0; ni < 2; ni++)
#pragma unroll
      for (int i = 0; i < 4; i++) {
        int t = t0 + wr * 32 + mi * 16 + lhi * 4 + i;
        int c = c0 + wc * 32 + ni * 16 + l16;
        atomicAdd(&out1[(size_t)(b * 512 + t) * 256 + c], acc[mi][ni][i]);
      }
}

extern "C" void kernel_launch(void* const* d_in, const int* in_sizes, int n_in,
                              void* d_out, int out_size, void* d_ws, size_t ws_size,
                              hipStream_t stream) {
  const float* Fs = (const float*)d_in[0];   // [8][256][4096]
  const float* Ft = (const float*)d_in[1];   // [8][512][256]
  float* out0 = (float*)d_out;               // [8][256][4096]
  float* out1 = out0 + (size_t)8 * 256 * 4096;  // [8][512][256]

  unsigned short* ws = (unsigned short*)d_ws;
  unsigned short* Q  = ws;               // [8][4096][256]  8,388,608
  unsigned short* QT = Q + 8388608;      // [8][256][4096]  8,388,608
  unsigned short* K  = QT + 8388608;     // [8][512][256]   1,048,576
  unsigned short* VT = K + 1048576;      // [8][256][512]   1,048,576
  unsigned short* PT = VT + 1048576;     // [8][512][4096] 16,777,216
  // total ws use: 71,303,168 bytes

  hipMemsetAsync(out1, 0, (size_t)1048576 * sizeof(float), stream);
  k_cast_transpose<<<dim3(128, 8, 8), 256, 0, stream>>>(Fs, QT, Q, 256, 4096);
  k_cast_transpose<<<dim3(8, 16, 8), 256, 0, stream>>>(Ft, K, VT, 512, 256);
  k_attn<<<dim3(128, 8), 256, 0, stream>>>(Q, K, VT, Fs, out0, PT);
  k_ptq<<<dim3(8, 4, 32), 256, 0, stream>>>(PT, QT, out1);
}